// Round 5
// baseline (458.266 us; speedup 1.0000x reference)
//
#include <hip/hip_runtime.h>
#include <hip/hip_bf16.h>
#include <math.h>

#define TOKENS 32768
#define DIM    2048
#define NEXP   64
#define TOPK   6
#define NKS    (DIM / 32)      // 64 MFMA K-steps

typedef float f32x4 __attribute__((ext_vector_type(4)));
typedef short sh8  __attribute__((ext_vector_type(8)));

__device__ __forceinline__ ushort f2bf(float f) {
    union { __hip_bfloat16 b; ushort u; } c;
    c.b = __float2bfloat16(f);
    return c.u;
}
__device__ __forceinline__ float bf2f(ushort u) {
    union { ushort u; __hip_bfloat16 b; } c;
    c.u = u;
    return __bfloat162float(c.b);
}

// ---- pre-kernel: split W into 3 exact bf16 planes (row-major = B-frag-ready) ----
__global__ __launch_bounds__(256)
void wsplit_kernel(const float* __restrict__ w,
                   short* __restrict__ wh, short* __restrict__ wm,
                   short* __restrict__ wl)
{
    const int i = (blockIdx.x * 256 + threadIdx.x) * 4;
    float4 f4 = *(const float4*)(w + i);
    short h4[4], m4[4], l4[4];
#pragma unroll
    for (int j = 0; j < 4; ++j) {
        float f = ((const float*)&f4)[j];
        ushort h = f2bf(f);  float r1 = f - bf2f(h);
        ushort m = f2bf(r1); float r2 = r1 - bf2f(m);
        h4[j] = (short)h; m4[j] = (short)m; l4[j] = (short)f2bf(r2);
    }
    *(short4*)(wh + i) = *(short4*)h4;
    *(short4*)(wm + i) = *(short4*)m4;
    *(short4*)(wl + i) = *(short4*)l4;
}

// ---- main: barrier-free K-loop, MFMA frags built straight from global ----
__global__ __launch_bounds__(256, 2)
void gate_kernel(const float* __restrict__ x,
                 const short* __restrict__ wh,
                 const short* __restrict__ wm,
                 const short* __restrict__ wl,
                 const float* __restrict__ bias,
                 float* __restrict__ out)
{
    __shared__ float red[64 * 69];

    const int tid  = threadIdx.x;
    const int wave = tid >> 6;
    const int lane = tid & 63;
    const int quad = lane >> 4;
    const int l15  = lane & 15;
    const int tg   = wave >> 1;     // token half: 32 tokens
    const int eg   = wave & 1;      // expert half: 32 experts
    const int tok0 = blockIdx.x * 64;

    const float* xr[2];
#pragma unroll
    for (int mt = 0; mt < 2; ++mt)
        xr[mt] = x + (long)(tok0 + tg * 32 + mt * 16 + l15) * DIM + quad * 8;

    long brow[2];
#pragma unroll
    for (int nt = 0; nt < 2; ++nt)
        brow[nt] = (long)(eg * 32 + nt * 16 + l15) * DIM + quad * 8;

    f32x4 acc[2][2];
#pragma unroll
    for (int mt = 0; mt < 2; ++mt)
#pragma unroll
        for (int nt = 0; nt < 2; ++nt)
            acc[mt][nt] = (f32x4){0.f, 0.f, 0.f, 0.f};

    // pipeline registers (next step)
    f32x4 xa[2][2];
    sh8 nbh[2], nbm[2], nbl[2];

    // prolog: step-0 loads
#pragma unroll
    for (int mt = 0; mt < 2; ++mt) {
        xa[mt][0] = *(const f32x4*)(xr[mt]);
        xa[mt][1] = *(const f32x4*)(xr[mt] + 4);
    }
#pragma unroll
    for (int nt = 0; nt < 2; ++nt) {
        nbh[nt] = *(const sh8*)(wh + brow[nt]);
        nbm[nt] = *(const sh8*)(wm + brow[nt]);
        nbl[nt] = *(const sh8*)(wl + brow[nt]);
    }

#pragma unroll 2
    for (int ks = 0; ks < NKS; ++ks) {
        // capture current step operands
        f32x4 ca[2][2];
        sh8 cbh[2], cbm[2], cbl[2];
#pragma unroll
        for (int mt = 0; mt < 2; ++mt) { ca[mt][0] = xa[mt][0]; ca[mt][1] = xa[mt][1]; }
#pragma unroll
        for (int nt = 0; nt < 2; ++nt) { cbh[nt] = nbh[nt]; cbm[nt] = nbm[nt]; cbl[nt] = nbl[nt]; }

        // issue next step's loads first (hidden under convert + MFMA below)
        if (ks + 1 < NKS) {
            const int k0 = (ks + 1) * 32;
#pragma unroll
            for (int mt = 0; mt < 2; ++mt) {
                xa[mt][0] = *(const f32x4*)(xr[mt] + k0);
                xa[mt][1] = *(const f32x4*)(xr[mt] + k0 + 4);
            }
#pragma unroll
            for (int nt = 0; nt < 2; ++nt) {
                nbh[nt] = *(const sh8*)(wh + brow[nt] + k0);
                nbm[nt] = *(const sh8*)(wm + brow[nt] + k0);
                nbl[nt] = *(const sh8*)(wl + brow[nt] + k0);
            }
        }

        // exact 3-plane split of current x frags (f == h + m + l)
        sh8 ah[2], am[2], al[2];
#pragma unroll
        for (int mt = 0; mt < 2; ++mt) {
#pragma unroll
            for (int i = 0; i < 8; ++i) {
                float f = ((const float*)&ca[mt][i >> 2])[i & 3];
                ushort h = f2bf(f);  float r1 = f - bf2f(h);
                ushort m = f2bf(r1); float r2 = r1 - bf2f(m);
                ah[mt][i] = (short)h; am[mt][i] = (short)m; al[mt][i] = (short)f2bf(r2);
            }
        }

        // 6 plane-products, plane-major so consecutive MFMAs hit independent accs
#pragma unroll
        for (int mt = 0; mt < 2; ++mt)
#pragma unroll
            for (int nt = 0; nt < 2; ++nt)
                acc[mt][nt] = __builtin_amdgcn_mfma_f32_16x16x32_bf16(ah[mt], cbh[nt], acc[mt][nt], 0, 0, 0);
#pragma unroll
        for (int mt = 0; mt < 2; ++mt)
#pragma unroll
            for (int nt = 0; nt < 2; ++nt)
                acc[mt][nt] = __builtin_amdgcn_mfma_f32_16x16x32_bf16(am[mt], cbh[nt], acc[mt][nt], 0, 0, 0);
#pragma unroll
        for (int mt = 0; mt < 2; ++mt)
#pragma unroll
            for (int nt = 0; nt < 2; ++nt)
                acc[mt][nt] = __builtin_amdgcn_mfma_f32_16x16x32_bf16(ah[mt], cbm[nt], acc[mt][nt], 0, 0, 0);
#pragma unroll
        for (int mt = 0; mt < 2; ++mt)
#pragma unroll
            for (int nt = 0; nt < 2; ++nt)
                acc[mt][nt] = __builtin_amdgcn_mfma_f32_16x16x32_bf16(al[mt], cbh[nt], acc[mt][nt], 0, 0, 0);
#pragma unroll
        for (int mt = 0; mt < 2; ++mt)
#pragma unroll
            for (int nt = 0; nt < 2; ++nt)
                acc[mt][nt] = __builtin_amdgcn_mfma_f32_16x16x32_bf16(am[mt], cbm[nt], acc[mt][nt], 0, 0, 0);
#pragma unroll
        for (int mt = 0; mt < 2; ++mt)
#pragma unroll
            for (int nt = 0; nt < 2; ++nt)
                acc[mt][nt] = __builtin_amdgcn_mfma_f32_16x16x32_bf16(ah[mt], cbl[nt], acc[mt][nt], 0, 0, 0);
    }

    // ---- logits -> red LDS (stride 69, conflict-free) ----
#pragma unroll
    for (int mt = 0; mt < 2; ++mt)
#pragma unroll
        for (int nt = 0; nt < 2; ++nt)
#pragma unroll
            for (int j = 0; j < 4; ++j) {
                const int row = tg * 32 + mt * 16 + quad * 4 + j;   // token
                const int col = eg * 32 + nt * 16 + l15;            // expert
                red[row * 69 + col] = acc[mt][nt][j];
            }
    __syncthreads();

    // ---- epilogue: softmax + bias + top-6, one thread per token ----
    if (tid < 64) {
        const int m = tid;
        float lg[NEXP];
#pragma unroll
        for (int e = 0; e < NEXP; ++e) lg[e] = red[m * 69 + e];

        float mx = lg[0];
#pragma unroll
        for (int e = 1; e < NEXP; ++e) mx = fmaxf(mx, lg[e]);

        float sc4[NEXP];
        float sum = 0.f;
#pragma unroll
        for (int e = 0; e < NEXP; ++e) { sc4[e] = __expf(lg[e] - mx); sum += sc4[e]; }
        const float inv = 1.0f / sum;

        float bz[NEXP];
#pragma unroll
        for (int e = 0; e < NEXP; ++e) {
            sc4[e] *= inv;               // original softmax score (returned weight)
            bz[e]  = sc4[e] + bias[e];   // biased score (selection only)
        }

        const int tok = tok0 + m;
        float* wout = out + (long)tok * TOPK;
        float* iout = out + (long)TOKENS * TOPK + (long)tok * TOPK;

        int win[TOPK];
#pragma unroll
        for (int p = 0; p < TOPK; ++p) {
            float bmax = -INFINITY;
            int   best = 0;
            float bsc  = 0.f;
#pragma unroll
            for (int e = 0; e < NEXP; ++e) {
                bool skip = false;
#pragma unroll
                for (int pp = 0; pp < p; ++pp) skip = skip || (e == win[pp]);
                float v = skip ? -INFINITY : bz[e];
                if (v > bmax) { bmax = v; best = e; bsc = sc4[e]; } // strict > = lower-index tie-break
            }
            win[p]  = best;
            wout[p] = bsc;              // ROUTE_SCALE == 1.0
            iout[p] = (float)best;      // indices as fp32 values
        }
    }
}

extern "C" void kernel_launch(void* const* d_in, const int* in_sizes, int n_in,
                              void* d_out, int out_size, void* d_ws, size_t ws_size,
                              hipStream_t stream) {
    const float* x = (const float*)d_in[0];
    const float* w = (const float*)d_in[1];
    const float* b = (const float*)d_in[2];
    float* out = (float*)d_out;

    short* wh = (short*)d_ws;                    // 64*2048 shorts
    short* wm = wh + NEXP * DIM;
    short* wl = wm + NEXP * DIM;

    wsplit_kernel<<<dim3(NEXP * DIM / (256 * 4)), dim3(256), 0, stream>>>(w, wh, wm, wl);
    gate_kernel<<<dim3(TOKENS / 64), dim3(256), 0, stream>>>(x, wh, wm, wl, b, out);
}